// Round 18
// baseline (294.237 us; speedup 1.0000x reference)
//
#include <hip/hip_runtime.h>
#include <stdint.h>
#include <limits.h>

#define IN_C   16
#define OUT_C  16
#define EDGE_DIM 8
#define HID    32
#define HSTR   20      // H LDS row stride in dwords
#define XSTR   20      // x LDS row stride in floats
#define MAXDEG 48      // fixed per-node msg capacity (max degree ~35 for E/N=16)
#define FEPB   128     // edges per fused block (2 waves)

typedef __attribute__((ext_vector_type(8))) short short8v;  // bf16x8 MFMA frag
typedef __attribute__((ext_vector_type(4))) float f32x4;

__device__ __forceinline__ uint32_t pack_bf16(float a, float b) {
    union { float f; uint32_t u; } ua, ub;
    ua.f = a; ub.f = b;
    uint32_t lo = (ua.u + 0x7FFFu + ((ua.u >> 16) & 1u)) >> 16;   // RNE
    uint32_t hi = (ub.u + 0x7FFFu + ((ub.u >> 16) & 1u)) >> 16;
    return (lo & 0xFFFFu) | (hi << 16);
}

// blocks [0,4): pre-pack W2 into per-lane MFMA B-fragments (bf16).
// blocks [4,...): grid-stride zero of cur[] and ovf[].
__global__ __launch_bounds__(256) void nnconv_prep(
    const float* __restrict__ W2, uint4* __restrict__ W2p,
    int* __restrict__ zero_base, int n_zero_ints)
{
    int bid = blockIdx.x;
    if (bid < 4) {
        int idx = bid * 256 + threadIdx.x;      // 0..1023 = ci*64 + l
        int ci = idx >> 6, l = idx & 63;
        int o = l & 15, g = l >> 4;
        uint32_t u[4];
        #pragma unroll
        for (int v = 0; v < 4; ++v) {
            int k0 = g * 8 + 2 * v;
            u[v] = pack_bf16(W2[(size_t)k0 * 256 + ci * 16 + o],
                             W2[(size_t)(k0 + 1) * 256 + ci * 16 + o]);
        }
        W2p[idx] = make_uint4(u[0], u[1], u[2], u[3]);
        return;
    }
    int t = (bid - 4) * 256 + threadIdx.x;
    int stride = (gridDim.x - 4) * 256;
    for (int i = t; i < n_zero_ints; i += stride)
        zero_base[i] = 0;
}

// ============ TIER 1: fused MLP+GEMM; atomic issued post-MLP; GEMM is vmem-free ============
// Per-wave LDS locality for Hl/xl (no barrier). Wl (W2p copy) is written
// REDUNDANTLY by each wave (identical values -> benign race, no barrier).
// After the rank atomic is issued there are NO vmem ops until its use at the
// final shuffle -> its ~3000cyc round-trip hides under the LDS-only GEMM.
__global__ __launch_bounds__(256, 2) void nnconv_fused1(
    const float* __restrict__ pseudo, const int* __restrict__ eidx,
    const float* __restrict__ x,
    const float* __restrict__ W1, const float* __restrict__ b1,
    const uint4* __restrict__ W2p, const float* __restrict__ b2,
    int* __restrict__ cur, float* __restrict__ ovf,
    float* __restrict__ msg, int n_edges)
{
    __shared__ uint32_t Hl[FEPB * HSTR];
    __shared__ float    xl[FEPB * XSTR];
    __shared__ uint4    Wl[1024];            // 16 KB block-shared B-fragments

    int t  = threadIdx.x;
    int e0 = blockIdx.x * FEPB;
    int e  = e0 + t;
    bool valid = e < n_edges;
    int lane = t & 63, w = t >> 6;

    // ---- stage: issue x + pseudo + W2p loads (NO atomic yet) ----
    int row = 0;
    float p[EDGE_DIM];
    {
        float4* xd = reinterpret_cast<float4*>(&xl[t * XSTR]);
        if (valid) {
            row = eidx[e];
            int c = eidx[n_edges + e];
            const float4* xp = reinterpret_cast<const float4*>(x + (size_t)c * IN_C);
            xd[0] = xp[0]; xd[1] = xp[1]; xd[2] = xp[2]; xd[3] = xp[3];
            const float4* pp = reinterpret_cast<const float4*>(pseudo + (size_t)e * EDGE_DIM);
            float4 p0 = pp[0], p1 = pp[1];
            p[0]=p0.x; p[1]=p0.y; p[2]=p0.z; p[3]=p0.w;
            p[4]=p1.x; p[5]=p1.y; p[6]=p1.z; p[7]=p1.w;
        } else {
            float4 z = make_float4(0.f, 0.f, 0.f, 0.f);
            xd[0] = z; xd[1] = z; xd[2] = z; xd[3] = z;
            #pragma unroll
            for (int k = 0; k < EDGE_DIM; ++k) p[k] = 0.f;
        }
        // each wave copies the whole 16 KB (identical values; L2-hot)
        #pragma unroll
        for (int k = 0; k < 16; ++k)
            Wl[lane + k * 64] = W2p[lane + k * 64];
    }

    // ---- MLP (k-outer: W1 rows contiguous -> wide wave-uniform scalar loads) ----
    {
        float h[HID];
        #pragma unroll
        for (int j = 0; j < HID; ++j) h[j] = b1[j];
        #pragma unroll
        for (int k = 0; k < EDGE_DIM; ++k) {
            float pk = p[k];
            const float* wr = W1 + k * HID;
            #pragma unroll
            for (int j = 0; j < HID; ++j)
                h[j] = fmaf(pk, wr[j], h[j]);
        }
        uint32_t hw[16];
        #pragma unroll
        for (int v = 0; v < 16; ++v) {
            float a0 = h[2*v]   > 0.f ? h[2*v]   : 0.f;
            float a1 = h[2*v+1] > 0.f ? h[2*v+1] : 0.f;
            hw[v] = valid ? pack_bf16(a0, a1) : 0u;
        }
        uint4* hp = reinterpret_cast<uint4*>(&Hl[t * HSTR]);
        hp[0] = make_uint4(hw[0],  hw[1],  hw[2],  hw[3]);
        hp[1] = make_uint4(hw[4],  hw[5],  hw[6],  hw[7]);
        hp[2] = make_uint4(hw[8],  hw[9],  hw[10], hw[11]);
        hp[3] = make_uint4(hw[12], hw[13], hw[14], hw[15]);
    }

    // ---- rank atomic: issued NOW; next vmem wait is at the final shuffle ----
    int slv = INT_MIN;
    int rank = 0;
    if (valid) rank = atomicAdd(&cur[row], 1);

    int o = lane & 15, g = lane >> 4;
    int ebase = w * 64;

    float b2v[16];
    #pragma unroll
    for (int ci = 0; ci < 16; ++ci) b2v[ci] = b2[ci * 16 + o];

    float maccs[4][4];

    // ---- GEMM: all operands from LDS/regs (q-outer, macc[4] live) ----
    #pragma unroll
    for (int q = 0; q < 4; ++q) {
        short8v A = *reinterpret_cast<const short8v*>(
            &Hl[(size_t)(ebase + q * 16 + o) * HSTR + g * 4]);
        float macc[4] = {0.f, 0.f, 0.f, 0.f};
        #pragma unroll
        for (int cq = 0; cq < 4; ++cq) {
            short8v Bf[4];
            #pragma unroll
            for (int j = 0; j < 4; ++j)
                Bf[j] = *reinterpret_cast<const short8v*>(&Wl[(cq * 4 + j) * 64 + lane]);
            f32x4 C[4];
            #pragma unroll
            for (int j = 0; j < 4; ++j) {
                float bb = b2v[cq * 4 + j];
                C[j] = __builtin_amdgcn_mfma_f32_16x16x32_bf16(
                    A, Bf[j], (f32x4){bb, bb, bb, bb}, 0, 0, 0);
            }
            #pragma unroll
            for (int r = 0; r < 4; ++r) {
                int el = ebase + q * 16 + g * 4 + r;
                float4 xa = *reinterpret_cast<const float4*>(&xl[el * XSTR + cq * 4]);
                float m = macc[r];
                m = fmaf(xa.x, C[0][r], m); m = fmaf(xa.y, C[1][r], m);
                m = fmaf(xa.z, C[2][r], m); m = fmaf(xa.w, C[3][r], m);
                macc[r] = m;
            }
        }
        #pragma unroll
        for (int r = 0; r < 4; ++r) maccs[q][r] = macc[r];
    }

    // ---- consume atomic (first vmem wait since issue) + scatter ----
    if (valid) slv = (rank < MAXDEG) ? (row * MAXDEG + rank) : (-row - 1);
    #pragma unroll
    for (int q = 0; q < 4; ++q)
        #pragma unroll
        for (int r = 0; r < 4; ++r) {
            int el = q * 16 + g * 4 + r;               // wave-local 0..63
            int sl = __shfl(slv, el, 64);
            if (sl >= 0)
                msg[(size_t)sl * OUT_C + o] = maccs[q][r];
            else if (sl != INT_MIN)
                atomicAdd(&ovf[(size_t)(-sl - 1) * OUT_C + o], maccs[q][r]);
        }
}

// wave per node: out = bias + x@root + sum msg rows + ovf
__global__ __launch_bounds__(256) void nnconv_gather1(
    const float* __restrict__ msg, const int* __restrict__ cur,
    const float* __restrict__ ovf, const float* __restrict__ x,
    const float* __restrict__ root, const float* __restrict__ bias,
    float* __restrict__ out, int n_nodes)
{
    int wave = threadIdx.x >> 6, lane = threadIdx.x & 63;
    int n = blockIdx.x * 4 + wave;
    if (n >= n_nodes) return;
    int group = lane >> 4, o = lane & 15;
    int cntn = cur[n]; if (cntn > MAXDEG) cntn = MAXDEG;
    size_t s = (size_t)n * MAXDEG;
    float acc = 0.f;
    for (int k = group; k < cntn; k += 4)
        acc += msg[(s + k) * OUT_C + o];
    acc += __shfl_xor(acc, 16, 64);
    acc += __shfl_xor(acc, 32, 64);
    if (group == 0) {
        float r = bias[o] + ovf[(size_t)n * OUT_C + o];
        const float* xr = x + (size_t)n * IN_C;
        #pragma unroll
        for (int i = 0; i < IN_C; ++i)
            r = fmaf(xr[i], root[i * OUT_C + o], r);
        out[n * OUT_C + o] = r + acc;
    }
}

// ============ TIER 3: direct-atomic fallback ============

__global__ __launch_bounds__(256) void nnconv_init_out(
    const float* __restrict__ x, const float* __restrict__ root,
    const float* __restrict__ bias, float* __restrict__ out, int n_nodes)
{
    int t = blockIdx.x * blockDim.x + threadIdx.x;
    if (t >= n_nodes * OUT_C) return;
    int n = t >> 4, o = t & 15;
    float acc = bias[o];
    #pragma unroll
    for (int i = 0; i < IN_C; ++i)
        acc = fmaf(x[n * IN_C + i], root[i * OUT_C + o], acc);
    out[t] = acc;
}

__global__ __launch_bounds__(256) void nnconv_edge_atomic(
    const float* __restrict__ x, const int* __restrict__ edge_index,
    const float* __restrict__ pseudo,
    const float* __restrict__ W1, const float* __restrict__ b1,
    const float* __restrict__ W2, const float* __restrict__ b2,
    float* __restrict__ out, int n_edges)
{
    int e = blockIdx.x * blockDim.x + threadIdx.x;
    if (e >= n_edges) return;
    int row = edge_index[e];
    int col = edge_index[n_edges + e];
    float p[EDGE_DIM];
    const float4* pp = reinterpret_cast<const float4*>(pseudo + (size_t)e * EDGE_DIM);
    float4 p0 = pp[0], p1 = pp[1];
    p[0]=p0.x; p[1]=p0.y; p[2]=p0.z; p[3]=p0.w;
    p[4]=p1.x; p[5]=p1.y; p[6]=p1.z; p[7]=p1.w;
    float h[HID];
    #pragma unroll
    for (int j = 0; j < HID; ++j) {
        float a = b1[j];
        #pragma unroll
        for (int k = 0; k < EDGE_DIM; ++k)
            a = fmaf(p[k], W1[k * HID + j], a);
        h[j] = a > 0.f ? a : 0.f;
    }
    float xg[IN_C];
    const float4* xp = reinterpret_cast<const float4*>(x + (size_t)col * IN_C);
    #pragma unroll
    for (int q = 0; q < 4; ++q) {
        float4 v = xp[q];
        xg[q*4+0]=v.x; xg[q*4+1]=v.y; xg[q*4+2]=v.z; xg[q*4+3]=v.w;
    }
    float m[OUT_C];
    #pragma unroll
    for (int o = 0; o < OUT_C; ++o) m[o] = 0.f;
    for (int i = 0; i < IN_C; ++i) {
        float wv[OUT_C];
        const float* b2r = b2 + i * OUT_C;
        #pragma unroll
        for (int o = 0; o < OUT_C; ++o) wv[o] = b2r[o];
        #pragma unroll
        for (int j = 0; j < HID; ++j) {
            float hj = h[j];
            const float* wr = W2 + j * (IN_C * OUT_C) + i * OUT_C;
            #pragma unroll
            for (int o = 0; o < OUT_C; ++o)
                wv[o] = fmaf(hj, wr[o], wv[o]);
        }
        float xi = xg[i];
        #pragma unroll
        for (int o = 0; o < OUT_C; ++o)
            m[o] = fmaf(xi, wv[o], m[o]);
    }
    float* op = out + (size_t)row * OUT_C;
    #pragma unroll
    for (int o = 0; o < OUT_C; ++o)
        atomicAdd(op + o, m[o]);
}

// ---------------- launch ----------------

extern "C" void kernel_launch(void* const* d_in, const int* in_sizes, int n_in,
                              void* d_out, int out_size, void* d_ws, size_t ws_size,
                              hipStream_t stream) {
    const float* x      = (const float*)d_in[0];
    const int*   eidx   = (const int*)  d_in[1];
    const float* pseudo = (const float*)d_in[2];
    const float* W1     = (const float*)d_in[3];
    const float* b1     = (const float*)d_in[4];
    const float* W2     = (const float*)d_in[5];
    const float* b2     = (const float*)d_in[6];
    const float* root   = (const float*)d_in[7];
    const float* bias   = (const float*)d_in[8];
    float* out = (float*)d_out;

    int n_nodes = in_sizes[0] / IN_C;
    int n_edges = in_sizes[1] / 2;
    int eblocks256 = (n_edges + 255) / 256;
    char* wsp = (char*)d_ws;

    // ---- tier 1 layout: cur[N] ovf[N*16 f32] |256| W2p[1024 u4] |256| msg[N*MAXDEG*16] ----
    {
        int* cur1  = (int*)wsp;
        float* ovf = (float*)(cur1 + n_nodes);
        size_t off = sizeof(int) * (size_t)n_nodes + sizeof(float) * (size_t)n_nodes * OUT_C;
        off = (off + 255) & ~(size_t)255;
        uint4* W2p = (uint4*)(wsp + off);
        off += sizeof(uint4) * 1024;
        off = (off + 255) & ~(size_t)255;
        float* msg = (float*)(wsp + off);
        size_t need = off + sizeof(float) * (size_t)n_nodes * MAXDEG * OUT_C;

        if (ws_size >= need) {
            int n_zero_ints = n_nodes + n_nodes * OUT_C;   // cur + ovf (contiguous)
            nnconv_prep<<<4 + 64, 256, 0, stream>>>(W2, W2p, cur1, n_zero_ints);
            nnconv_fused1<<<(n_edges + FEPB - 1) / FEPB, FEPB, 0, stream>>>(
                pseudo, eidx, x, W1, b1, W2p, b2, cur1, ovf, msg, n_edges);
            nnconv_gather1<<<(n_nodes + 3) / 4, 256, 0, stream>>>(
                msg, cur1, ovf, x, root, bias, out, n_nodes);
            return;
        }
    }

    nnconv_init_out<<<(n_nodes * OUT_C + 255) / 256, 256, 0, stream>>>(
        x, root, bias, out, n_nodes);
    nnconv_edge_atomic<<<eblocks256, 256, 0, stream>>>(
        x, eidx, pseudo, W1, b1, W2, b2, out, n_edges);
}

// Round 19
// 76.263 us; speedup vs baseline: 3.8582x; 3.8582x over previous
//
#include <hip/hip_runtime.h>
#include <stdint.h>
#include <limits.h>

#define IN_C   16
#define OUT_C  16
#define EDGE_DIM 8
#define HID    32
#define HSTR   20      // H LDS row stride in dwords
#define XSTR   20      // x LDS row stride in floats
#define MAXDEG 48      // fixed per-node msg capacity (max degree ~35 for E/N=16)
#define FEPB   128     // edges per fused block (2 waves)

typedef __attribute__((ext_vector_type(8))) short short8v;  // bf16x8 MFMA frag
typedef __attribute__((ext_vector_type(4))) float f32x4;

__device__ __forceinline__ uint32_t pack_bf16(float a, float b) {
    union { float f; uint32_t u; } ua, ub;
    ua.f = a; ub.f = b;
    uint32_t lo = (ua.u + 0x7FFFu + ((ua.u >> 16) & 1u)) >> 16;   // RNE
    uint32_t hi = (ub.u + 0x7FFFu + ((ub.u >> 16) & 1u)) >> 16;
    return (lo & 0xFFFFu) | (hi << 16);
}

// blocks [0,4): pre-pack W2 into per-lane MFMA B-fragments (bf16).
// blocks [4,...): grid-stride zero of cur[] and ovf[].
__global__ __launch_bounds__(256) void nnconv_prep(
    const float* __restrict__ W2, uint4* __restrict__ W2p,
    int* __restrict__ zero_base, int n_zero_ints)
{
    int bid = blockIdx.x;
    if (bid < 4) {
        int idx = bid * 256 + threadIdx.x;      // 0..1023 = ci*64 + l
        int ci = idx >> 6, l = idx & 63;
        int o = l & 15, g = l >> 4;
        uint32_t u[4];
        #pragma unroll
        for (int v = 0; v < 4; ++v) {
            int k0 = g * 8 + 2 * v;
            u[v] = pack_bf16(W2[(size_t)k0 * 256 + ci * 16 + o],
                             W2[(size_t)(k0 + 1) * 256 + ci * 16 + o]);
        }
        W2p[idx] = make_uint4(u[0], u[1], u[2], u[3]);
        return;
    }
    int t = (bid - 4) * 256 + threadIdx.x;
    int stride = (gridDim.x - 4) * 256;
    for (int i = t; i < n_zero_ints; i += stride)
        zero_base[i] = 0;
}

// ============ TIER 1: fused MLP+GEMM; LDS-resident W2p; atomic post-MLP ============
// R17 register shape (q-outer, macc[4], per-q scatter; ~120 VGPR under cap 128).
// Wl copied in 4-uint4 chunks BEFORE the MLP (temps die before h[32] lives);
// each wave writes the full table redundantly (identical values -> benign race,
// no barrier). Rank atomic issued AFTER all vmem loads: no vmem op exists
// between it and its first consume (q0 store) -> round-trip hides under GEMM.
__global__ __launch_bounds__(256, 2) void nnconv_fused1(
    const float* __restrict__ pseudo, const int* __restrict__ eidx,
    const float* __restrict__ x,
    const float* __restrict__ W1, const float* __restrict__ b1,
    const uint4* __restrict__ W2p, const float* __restrict__ b2,
    int* __restrict__ cur, float* __restrict__ ovf,
    float* __restrict__ msg, int n_edges)
{
    __shared__ uint32_t Hl[FEPB * HSTR];
    __shared__ float    xl[FEPB * XSTR];
    __shared__ uint4    Wl[1024];            // 16 KB block-shared B-fragments

    int t  = threadIdx.x;
    int e0 = blockIdx.x * FEPB;
    int e  = e0 + t;
    bool valid = e < n_edges;
    int lane = t & 63, w = t >> 6;
    int o = lane & 15, g = lane >> 4;

    // ---- stage: x + pseudo + b2 loads ----
    int row = 0;
    float p[EDGE_DIM];
    {
        float4* xd = reinterpret_cast<float4*>(&xl[t * XSTR]);
        if (valid) {
            row = eidx[e];
            int c = eidx[n_edges + e];
            const float4* xp = reinterpret_cast<const float4*>(x + (size_t)c * IN_C);
            xd[0] = xp[0]; xd[1] = xp[1]; xd[2] = xp[2]; xd[3] = xp[3];
            const float4* pp = reinterpret_cast<const float4*>(pseudo + (size_t)e * EDGE_DIM);
            float4 p0 = pp[0], p1 = pp[1];
            p[0]=p0.x; p[1]=p0.y; p[2]=p0.z; p[3]=p0.w;
            p[4]=p1.x; p[5]=p1.y; p[6]=p1.z; p[7]=p1.w;
        } else {
            float4 z = make_float4(0.f, 0.f, 0.f, 0.f);
            xd[0] = z; xd[1] = z; xd[2] = z; xd[3] = z;
            #pragma unroll
            for (int k = 0; k < EDGE_DIM; ++k) p[k] = 0.f;
        }
    }
    float b2v[16];
    #pragma unroll
    for (int ci = 0; ci < 16; ++ci) b2v[ci] = b2[ci * 16 + o];

    // ---- Wl copy: 4 chunks of 4 uint4 (16 VGPR in flight max) ----
    for (int ch = 0; ch < 4; ++ch) {
        uint4 c0 = W2p[lane + (ch * 4 + 0) * 64];
        uint4 c1 = W2p[lane + (ch * 4 + 1) * 64];
        uint4 c2 = W2p[lane + (ch * 4 + 2) * 64];
        uint4 c3 = W2p[lane + (ch * 4 + 3) * 64];
        Wl[lane + (ch * 4 + 0) * 64] = c0;
        Wl[lane + (ch * 4 + 1) * 64] = c1;
        Wl[lane + (ch * 4 + 2) * 64] = c2;
        Wl[lane + (ch * 4 + 3) * 64] = c3;
    }

    // ---- MLP (k-outer: W1 rows contiguous -> wide wave-uniform scalar loads) ----
    {
        float h[HID];
        #pragma unroll
        for (int j = 0; j < HID; ++j) h[j] = b1[j];
        #pragma unroll
        for (int k = 0; k < EDGE_DIM; ++k) {
            float pk = p[k];
            const float* wr = W1 + k * HID;
            #pragma unroll
            for (int j = 0; j < HID; ++j)
                h[j] = fmaf(pk, wr[j], h[j]);
        }
        uint32_t hw[16];
        #pragma unroll
        for (int v = 0; v < 16; ++v) {
            float a0 = h[2*v]   > 0.f ? h[2*v]   : 0.f;
            float a1 = h[2*v+1] > 0.f ? h[2*v+1] : 0.f;
            hw[v] = valid ? pack_bf16(a0, a1) : 0u;
        }
        uint4* hp = reinterpret_cast<uint4*>(&Hl[t * HSTR]);
        hp[0] = make_uint4(hw[0],  hw[1],  hw[2],  hw[3]);
        hp[1] = make_uint4(hw[4],  hw[5],  hw[6],  hw[7]);
        hp[2] = make_uint4(hw[8],  hw[9],  hw[10], hw[11]);
        hp[3] = make_uint4(hw[12], hw[13], hw[14], hw[15]);
    }
    // no barrier: every wave reads only its own 64 rows of Hl/xl; Wl identical

    // ---- rank atomic: last vmem op before the q0-store consume ----
    int slv = INT_MIN;
    if (valid) {
        int rank = atomicAdd(&cur[row], 1);
        slv = (rank < MAXDEG) ? (row * MAXDEG + rank) : (-row - 1);
    }

    int ebase = w * 64;

    // ---- GEMM: all operands from LDS/regs (q-outer, macc[4] live) ----
    #pragma unroll
    for (int q = 0; q < 4; ++q) {
        short8v A = *reinterpret_cast<const short8v*>(
            &Hl[(size_t)(ebase + q * 16 + o) * HSTR + g * 4]);
        float macc[4] = {0.f, 0.f, 0.f, 0.f};
        #pragma unroll
        for (int cq = 0; cq < 4; ++cq) {
            short8v Bf[4];
            #pragma unroll
            for (int j = 0; j < 4; ++j)
                Bf[j] = *reinterpret_cast<const short8v*>(&Wl[(cq * 4 + j) * 64 + lane]);
            f32x4 C[4];
            #pragma unroll
            for (int j = 0; j < 4; ++j) {
                float bb = b2v[cq * 4 + j];
                C[j] = __builtin_amdgcn_mfma_f32_16x16x32_bf16(
                    A, Bf[j], (f32x4){bb, bb, bb, bb}, 0, 0, 0);
            }
            #pragma unroll
            for (int r = 0; r < 4; ++r) {
                int el = ebase + q * 16 + g * 4 + r;
                float4 xa = *reinterpret_cast<const float4*>(&xl[el * XSTR + cq * 4]);
                float m = macc[r];
                m = fmaf(xa.x, C[0][r], m); m = fmaf(xa.y, C[1][r], m);
                m = fmaf(xa.z, C[2][r], m); m = fmaf(xa.w, C[3][r], m);
                macc[r] = m;
            }
        }
        #pragma unroll
        for (int r = 0; r < 4; ++r) {
            int el = q * 16 + g * 4 + r;               // wave-local 0..63
            int sl = __shfl(slv, el, 64);
            if (sl >= 0)
                msg[(size_t)sl * OUT_C + o] = macc[r];
            else if (sl != INT_MIN)
                atomicAdd(&ovf[(size_t)(-sl - 1) * OUT_C + o], macc[r]);
        }
    }
}

// wave per node: out = bias + x@root + sum msg rows + ovf
__global__ __launch_bounds__(256) void nnconv_gather1(
    const float* __restrict__ msg, const int* __restrict__ cur,
    const float* __restrict__ ovf, const float* __restrict__ x,
    const float* __restrict__ root, const float* __restrict__ bias,
    float* __restrict__ out, int n_nodes)
{
    int wave = threadIdx.x >> 6, lane = threadIdx.x & 63;
    int n = blockIdx.x * 4 + wave;
    if (n >= n_nodes) return;
    int group = lane >> 4, o = lane & 15;
    int cntn = cur[n]; if (cntn > MAXDEG) cntn = MAXDEG;
    size_t s = (size_t)n * MAXDEG;
    float acc = 0.f;
    for (int k = group; k < cntn; k += 4)
        acc += msg[(s + k) * OUT_C + o];
    acc += __shfl_xor(acc, 16, 64);
    acc += __shfl_xor(acc, 32, 64);
    if (group == 0) {
        float r = bias[o] + ovf[(size_t)n * OUT_C + o];
        const float* xr = x + (size_t)n * IN_C;
        #pragma unroll
        for (int i = 0; i < IN_C; ++i)
            r = fmaf(xr[i], root[i * OUT_C + o], r);
        out[n * OUT_C + o] = r + acc;
    }
}

// ============ TIER 3: direct-atomic fallback ============

__global__ __launch_bounds__(256) void nnconv_init_out(
    const float* __restrict__ x, const float* __restrict__ root,
    const float* __restrict__ bias, float* __restrict__ out, int n_nodes)
{
    int t = blockIdx.x * blockDim.x + threadIdx.x;
    if (t >= n_nodes * OUT_C) return;
    int n = t >> 4, o = t & 15;
    float acc = bias[o];
    #pragma unroll
    for (int i = 0; i < IN_C; ++i)
        acc = fmaf(x[n * IN_C + i], root[i * OUT_C + o], acc);
    out[t] = acc;
}

__global__ __launch_bounds__(256) void nnconv_edge_atomic(
    const float* __restrict__ x, const int* __restrict__ edge_index,
    const float* __restrict__ pseudo,
    const float* __restrict__ W1, const float* __restrict__ b1,
    const float* __restrict__ W2, const float* __restrict__ b2,
    float* __restrict__ out, int n_edges)
{
    int e = blockIdx.x * blockDim.x + threadIdx.x;
    if (e >= n_edges) return;
    int row = edge_index[e];
    int col = edge_index[n_edges + e];
    float p[EDGE_DIM];
    const float4* pp = reinterpret_cast<const float4*>(pseudo + (size_t)e * EDGE_DIM);
    float4 p0 = pp[0], p1 = pp[1];
    p[0]=p0.x; p[1]=p0.y; p[2]=p0.z; p[3]=p0.w;
    p[4]=p1.x; p[5]=p1.y; p[6]=p1.z; p[7]=p1.w;
    float h[HID];
    #pragma unroll
    for (int j = 0; j < HID; ++j) {
        float a = b1[j];
        #pragma unroll
        for (int k = 0; k < EDGE_DIM; ++k)
            a = fmaf(p[k], W1[k * HID + j], a);
        h[j] = a > 0.f ? a : 0.f;
    }
    float xg[IN_C];
    const float4* xp = reinterpret_cast<const float4*>(x + (size_t)col * IN_C);
    #pragma unroll
    for (int q = 0; q < 4; ++q) {
        float4 v = xp[q];
        xg[q*4+0]=v.x; xg[q*4+1]=v.y; xg[q*4+2]=v.z; xg[q*4+3]=v.w;
    }
    float m[OUT_C];
    #pragma unroll
    for (int o = 0; o < OUT_C; ++o) m[o] = 0.f;
    for (int i = 0; i < IN_C; ++i) {
        float wv[OUT_C];
        const float* b2r = b2 + i * OUT_C;
        #pragma unroll
        for (int o = 0; o < OUT_C; ++o) wv[o] = b2r[o];
        #pragma unroll
        for (int j = 0; j < HID; ++j) {
            float hj = h[j];
            const float* wr = W2 + j * (IN_C * OUT_C) + i * OUT_C;
            #pragma unroll
            for (int o = 0; o < OUT_C; ++o)
                wv[o] = fmaf(hj, wr[o], wv[o]);
        }
        float xi = xg[i];
        #pragma unroll
        for (int o = 0; o < OUT_C; ++o)
            m[o] = fmaf(xi, wv[o], m[o]);
    }
    float* op = out + (size_t)row * OUT_C;
    #pragma unroll
    for (int o = 0; o < OUT_C; ++o)
        atomicAdd(op + o, m[o]);
}

// ---------------- launch ----------------

extern "C" void kernel_launch(void* const* d_in, const int* in_sizes, int n_in,
                              void* d_out, int out_size, void* d_ws, size_t ws_size,
                              hipStream_t stream) {
    const float* x      = (const float*)d_in[0];
    const int*   eidx   = (const int*)  d_in[1];
    const float* pseudo = (const float*)d_in[2];
    const float* W1     = (const float*)d_in[3];
    const float* b1     = (const float*)d_in[4];
    const float* W2     = (const float*)d_in[5];
    const float* b2     = (const float*)d_in[6];
    const float* root   = (const float*)d_in[7];
    const float* bias   = (const float*)d_in[8];
    float* out = (float*)d_out;

    int n_nodes = in_sizes[0] / IN_C;
    int n_edges = in_sizes[1] / 2;
    int eblocks256 = (n_edges + 255) / 256;
    char* wsp = (char*)d_ws;

    // ---- tier 1 layout: cur[N] ovf[N*16 f32] |256| W2p[1024 u4] |256| msg[N*MAXDEG*16] ----
    {
        int* cur1  = (int*)wsp;
        float* ovf = (float*)(cur1 + n_nodes);
        size_t off = sizeof(int) * (size_t)n_nodes + sizeof(float) * (size_t)n_nodes * OUT_C;
        off = (off + 255) & ~(size_t)255;
        uint4* W2p = (uint4*)(wsp + off);
        off += sizeof(uint4) * 1024;
        off = (off + 255) & ~(size_t)255;
        float* msg = (float*)(wsp + off);
        size_t need = off + sizeof(float) * (size_t)n_nodes * MAXDEG * OUT_C;

        if (ws_size >= need) {
            int n_zero_ints = n_nodes + n_nodes * OUT_C;   // cur + ovf (contiguous)
            nnconv_prep<<<4 + 64, 256, 0, stream>>>(W2, W2p, cur1, n_zero_ints);
            nnconv_fused1<<<(n_edges + FEPB - 1) / FEPB, FEPB, 0, stream>>>(
                pseudo, eidx, x, W1, b1, W2p, b2, cur1, ovf, msg, n_edges);
            nnconv_gather1<<<(n_nodes + 3) / 4, 256, 0, stream>>>(
                msg, cur1, ovf, x, root, bias, out, n_nodes);
            return;
        }
    }

    nnconv_init_out<<<(n_nodes * OUT_C + 255) / 256, 256, 0, stream>>>(
        x, root, bias, out, n_nodes);
    nnconv_edge_atomic<<<eblocks256, 256, 0, stream>>>(
        x, eidx, pseudo, W1, b1, W2, b2, out, n_edges);
}